// Round 4
// baseline (376.093 us; speedup 1.0000x reference)
//
#include <hip/hip_runtime.h>

// y[b,c,m] = sum_{a<4, l<16} h[b,c,a,m,l] * x[b,a,m-l]   (m-l valid in [0,NT))
// Shapes: x[32,1,4,2048] f32, h[32,1,16,1,4,2063,16] f32, y[32,1,16,2063] f32.
// Memory-bound on h (270 MB single-pass stream). Floor ~44 us at 6.3 TB/s.
// R1 evidence: kernel absent from top-5 (all fills ~163us) => kernel <161us;
// dur_us=370 appears dominated by harness poison-fill/restore overhead.
// R3: __builtin_nontemporal_load needs a clang ext_vector_type, not HIP float4.

#define NTT 2048
#define LL  16
#define TT  2063
#define NC  16   // RXA
#define NA  4    // TXA
#define BM  256  // m per block
#define MT  ((TT + BM - 1) / BM)   // 9 m-tiles

typedef float f32x4 __attribute__((ext_vector_type(4)));

__global__ __launch_bounds__(BM) void atc_kernel(
    const float* __restrict__ x,   // [B,1,NA,NTT]
    const float* __restrict__ h,   // [B,1,NC,1,NA,TT,LL]
    float* __restrict__ y)         // [B,1,NC,TT]
{
    // x windows for this block's m-range [m0-15, m0+BM-1]: NA * (BM+15) floats
    __shared__ float xs[NA][BM + LL];  // 4 x 272 floats = 4.3 KB

    const int bid = blockIdx.x;
    const int mt  = bid % MT;
    const int c   = (bid / MT) % NC;
    const int b   = bid / (MT * NC);
    const int m0  = mt * BM;
    const int tid = threadIdx.x;

    const int WIN = BM + LL - 1;  // 271
    for (int i = tid; i < NA * WIN; i += BM) {
        const int a = i / WIN;
        const int j = i - a * WIN;
        const int tg = m0 - (LL - 1) + j;   // global time index
        float v = 0.0f;
        if (tg >= 0 && tg < NTT) v = x[(b * NA + a) * NTT + tg];
        xs[a][j] = v;
    }
    __syncthreads();

    const int m = m0 + tid;
    if (m < TT) {
        // Issue ALL 16 h loads up front (max memory-level parallelism).
        // Streaming data, zero reuse after this wave -> nontemporal.
        const f32x4* hp = reinterpret_cast<const f32x4*>(
            h + ((size_t)(b * NC + c) * NA * TT + m) * LL);
        const size_t astride = (size_t)TT * LL / 4;  // f32x4 stride between a's
        f32x4 hr[NA][4];
        #pragma unroll
        for (int a = 0; a < NA; ++a) {
            #pragma unroll
            for (int k = 0; k < 4; ++k) {
                hr[a][k] = __builtin_nontemporal_load(&hp[(size_t)a * astride + k]);
            }
        }

        float acc0 = 0.f, acc1 = 0.f, acc2 = 0.f, acc3 = 0.f;
        #pragma unroll
        for (int a = 0; a < NA; ++a) {
            // xs[a][tid + 15 - l] == x[b, a, m - l]
            const float* xw = &xs[a][tid];
            acc0 += hr[a][0].x * xw[15] + hr[a][0].y * xw[14] + hr[a][0].z * xw[13] + hr[a][0].w * xw[12];
            acc1 += hr[a][1].x * xw[11] + hr[a][1].y * xw[10] + hr[a][1].z * xw[ 9] + hr[a][1].w * xw[ 8];
            acc2 += hr[a][2].x * xw[ 7] + hr[a][2].y * xw[ 6] + hr[a][2].z * xw[ 5] + hr[a][2].w * xw[ 4];
            acc3 += hr[a][3].x * xw[ 3] + hr[a][3].y * xw[ 2] + hr[a][3].z * xw[ 1] + hr[a][3].w * xw[ 0];
        }
        y[(size_t)(b * NC + c) * TT + m] = (acc0 + acc1) + (acc2 + acc3);
    }
}

extern "C" void kernel_launch(void* const* d_in, const int* in_sizes, int n_in,
                              void* d_out, int out_size, void* d_ws, size_t ws_size,
                              hipStream_t stream) {
    const float* x = (const float*)d_in[0];
    const float* h = (const float*)d_in[1];
    // d_in[2] (g) unused: toeplitz indices are computed analytically.
    float* y = (float*)d_out;

    const int nblocks = 32 * NC * MT;  // 4608
    atc_kernel<<<nblocks, BM, 0, stream>>>(x, h, y);
}

// Round 5
// 359.052 us; speedup vs baseline: 1.0475x; 1.0475x over previous
//
#include <hip/hip_runtime.h>

// y[b,c,m] = sum_{a<4, l<16} h[b,c,a,m,l] * x[b,a,m-l]   (m-l valid in [0,NT))
// Shapes: x[32,1,4,2048] f32, h[32,1,16,1,4,2063,16] f32, y[32,1,16,2063] f32.
// Memory-bound on h (270 MB single-pass stream). Floor ~44 us at 6.3 TB/s.
// R1/R4 evidence: kernel absent from top-5 (fills ~163us @6.6TB/s) => K < 160us;
// dur_us ~373 for two structurally different kernels => large constant harness
// reset component O (ws poison 1.08GB ~163us + h restore 251MB ~76us + misc).
// R5: decisive coalescing test. 4 lanes per m, lane q owns taps 4q..4q+3.
// Every load instruction covers 1KB contiguous per wave (perfect coalescing),
// vs previous 64B-chunk-per-thread (16B sectors of 64 lines per instruction).

#define NTT 2048
#define LL  16
#define TT  2063
#define NC  16   // RXA
#define NA  4    // TXA
#define BMQ 64   // m per block (4 lanes per m, 256 threads)
#define MT  ((TT + BMQ - 1) / BMQ)   // 33 m-tiles

typedef float f32x4 __attribute__((ext_vector_type(4)));

__global__ __launch_bounds__(256) void atc_kernel(
    const float* __restrict__ x,   // [B,1,NA,NTT]
    const float* __restrict__ h,   // [B,1,NC,1,NA,TT,LL]
    float* __restrict__ y)         // [B,1,NC,TT]
{
    __shared__ float xs[NA][BMQ + LL];  // 4 x 80 floats = 1.25 KB

    const int bid = blockIdx.x;
    const int mt  = bid % MT;
    const int c   = (bid / MT) % NC;
    const int b   = bid / (MT * NC);
    const int m0  = mt * BMQ;
    const int tid = threadIdx.x;   // 0..255
    const int q   = tid & 3;       // tap group: l = 4q + r, r=0..3
    const int ml  = tid >> 2;      // local m index 0..63

    // Stage x windows [m0-15, m0+BMQ-1] for all 4 antennas (zero-pad edges)
    const int WIN = BMQ + LL - 1;  // 79
    for (int i = tid; i < NA * WIN; i += 256) {
        const int a = i / WIN;
        const int j = i - a * WIN;
        const int tg = m0 - (LL - 1) + j;
        xs[a][j] = (tg >= 0 && tg < NTT) ? x[(b * NA + a) * NTT + tg] : 0.0f;
    }
    __syncthreads();

    const int m = m0 + ml;
    float acc = 0.0f;
    if (m < TT) {
        // Lane (ml,q) loads 16B at h[b,c,a,m, 4q..4q+3] for each a.
        // Across a wave (q fastest, then ml): addresses are CONTIGUOUS ->
        // one 1KB fully-coalesced segment per load instruction.
        const f32x4* hp = reinterpret_cast<const f32x4*>(
            h + ((size_t)(b * NC + c) * NA * TT + m) * LL) + q;
        const size_t astride = (size_t)TT * LL / 4;  // f32x4 stride between a's
        f32x4 hv[NA];
        #pragma unroll
        for (int a = 0; a < NA; ++a) hv[a] = hp[(size_t)a * astride];

        #pragma unroll
        for (int a = 0; a < NA; ++a) {
            // tap l = 4q + r multiplies x[b,a,m-l] = xs[a][ml + 15 - 4q - r]
            const float* xw = &xs[a][ml + (LL - 1) - 4 * q];
            acc += hv[a].x * xw[0] + hv[a].y * xw[-1]
                 + hv[a].z * xw[-2] + hv[a].w * xw[-3];
        }
    }

    // Reduce the 4 tap-groups (lanes differing in low 2 bits share the same m)
    acc += __shfl_xor(acc, 1);
    acc += __shfl_xor(acc, 2);
    if (q == 0 && m < TT) {
        y[(size_t)(b * NC + c) * TT + m] = acc;
    }
}

extern "C" void kernel_launch(void* const* d_in, const int* in_sizes, int n_in,
                              void* d_out, int out_size, void* d_ws, size_t ws_size,
                              hipStream_t stream) {
    const float* x = (const float*)d_in[0];
    const float* h = (const float*)d_in[1];
    // d_in[2] (g) unused: toeplitz indices are computed analytically.
    float* y = (float*)d_out;

    const int nblocks = 32 * NC * MT;  // 16896
    atc_kernel<<<nblocks, 256, 0, stream>>>(x, h, y);
}